// Round 13
// baseline (318.700 us; speedup 1.0000x reference)
//
#include <hip/hip_runtime.h>
#include <hip/hip_bf16.h>

// LaplaceCostNet — MI355X (gfx950), round 13.
// R12 post-mortem: __launch_bounds__(512,2) caps ARCH VGPRs at 256/2 = 128
// (pattern: R5 (256,4)->64, R6 (256,2)->128, R10..R12 (512,2)->128). The ~190-reg
// dual-group dataflow spilled against that cap, twice. R13 = R12 verbatim with
// __launch_bounds__(512) (no waves-per-eu arg): 8-wave workgroup still forces
// <=2 waves/SIMD feasibility, budget 256 arch + acc. Tell: VGPR_Count ~180-250,
// WRITE_SIZE ~2 MB.
//
// Workspace (bytes):
//   [4096   .. 135168)   WT bf16: row n, physical 16B chunk P holds logical
//                        chunk P^(n&15)  (logical chunk cc = elems k=8cc..8cc+7)
//   [262144 .. +1MB)     C    fp32
//   [262144+3MB .. +4MB) Vfin fp32

typedef unsigned short ushort_t;
typedef short short8 __attribute__((ext_vector_type(8)));
typedef float floatx16 __attribute__((ext_vector_type(16)));
typedef unsigned int uintx4 __attribute__((ext_vector_type(4)));

#define HH 512
#define WW 512
#define NPIX (HH*WW)

__device__ inline unsigned int pk_bf16(float a, float b) {   // a->low16, b->high16
    __hip_bfloat162 h = __float22bfloat162_rn(float2{a, b});
    return *(unsigned int*)&h;
}
__device__ inline void async_copy16(void* lds, const void* g) {
    __builtin_amdgcn_global_load_lds(
        (const __attribute__((address_space(1))) unsigned int*)g,
        (__attribute__((address_space(3))) unsigned int*)lds, 16, 0, 0);
}

// ---------------- prep: DMA-ready swizzled WT (16B-chunk granularity) ----------------
__global__ __launch_bounds__(256) void prep_kernel(const float* __restrict__ Wh,
                                                   ushort_t* __restrict__ WT) {
    __shared__ float trans[32][129];
    const int t = threadIdx.x;
    const int l = blockIdx.x >> 2, n0 = (blockIdx.x & 3) * 32;
    const int nl = t & 31, k0 = t >> 5;            // k0 0..7
    #pragma unroll
    for (int pass = 0; pass < 16; ++pass) {
        int k = pass * 8 + k0;
        trans[nl][k] = Wh[l * 16384 + k * 128 + n0 + nl];   // coalesced in n
    }
    __syncthreads();
    #pragma unroll
    for (int c = 0; c < 2; ++c) {
        int idx = c * 256 + t;                      // 0..511 : 32 rows x 16 chunks
        int nl2 = idx >> 4, P = idx & 15;
        int n = n0 + nl2;
        int cc = P ^ (n & 15);                      // logical 16B chunk
        int kk = cc * 8;
        unsigned int w0 = pk_bf16(trans[nl2][kk + 0], trans[nl2][kk + 1]);
        unsigned int w1 = pk_bf16(trans[nl2][kk + 2], trans[nl2][kk + 3]);
        unsigned int w2 = pk_bf16(trans[nl2][kk + 4], trans[nl2][kk + 5]);
        unsigned int w3 = pk_bf16(trans[nl2][kk + 6], trans[nl2][kk + 7]);
        ((uint4*)WT)[(l * 128 + n) * 16 + P] = uint4{w0, w1, w2, w3};
    }
}

// C-layout block (8 floats at 8*par) -> B-frag for next layer (relu + pack + 1 shfl)
__device__ inline uintx4 xform(const floatx16& acc, int par, int Hh) {
    unsigned int u0 = pk_bf16(fmaxf(acc[8 * par + 0], 0.0f), fmaxf(acc[8 * par + 1], 0.0f));
    unsigned int u1 = pk_bf16(fmaxf(acc[8 * par + 2], 0.0f), fmaxf(acc[8 * par + 3], 0.0f));
    unsigned int u2 = pk_bf16(fmaxf(acc[8 * par + 4], 0.0f), fmaxf(acc[8 * par + 5], 0.0f));
    unsigned int u3 = pk_bf16(fmaxf(acc[8 * par + 6], 0.0f), fmaxf(acc[8 * par + 7], 0.0f));
    unsigned int s0 = Hh ? u0 : u2, s1 = Hh ? u1 : u3;   // send block
    unsigned int k0 = Hh ? u2 : u0, k1 = Hh ? u3 : u1;   // keep block
    unsigned int r0 = (unsigned int)__shfl_xor((int)s0, 32);
    unsigned int r1 = (unsigned int)__shfl_xor((int)s1, 32);
    uintx4 f;
    f[0] = Hh ? r0 : k0;
    f[1] = Hh ? r1 : k1;
    f[2] = Hh ? k0 : r0;
    f[3] = Hh ? k1 : r1;
    return f;
}

// one hidden layer, dual point-group; per-i acc (one floatx16 per group live)
__device__ inline void run_layer(const ushort_t* __restrict__ wl, int m, int Hh,
                                 const uintx4 (&iA)[8], const uintx4 (&iB)[8],
                                 uintx4 (&oA)[8], uintx4 (&oB)[8]) {
    #pragma unroll
    for (int i = 0; i < 4; ++i) {
        floatx16 aA = (floatx16)(0.0f), aB = (floatx16)(0.0f);
        #pragma unroll
        for (int ks = 0; ks < 8; ++ks) {
            int n = i * 32 + m;
            int cc = 2 * ks + Hh;
            short8 av = *(const short8*)&wl[(n << 7) + ((cc ^ (n & 15)) << 3)];
            aA = __builtin_amdgcn_mfma_f32_32x32x16_bf16(av, __builtin_bit_cast(short8, iA[ks]), aA, 0, 0, 0);
            aB = __builtin_amdgcn_mfma_f32_32x32x16_bf16(av, __builtin_bit_cast(short8, iB[ks]), aB, 0, 0, 0);
        }
        oA[2 * i]     = xform(aA, 0, Hh);
        oA[2 * i + 1] = xform(aA, 1, Hh);
        oB[2 * i]     = xform(aB, 0, Hh);
        oB[2 * i + 1] = xform(aB, 1, Hh);
    }
}

// ---------------- MLP: persistent, register-resident acts, dual point-group ----------------
__global__ __launch_bounds__(512) void mlp_kernel(const float* __restrict__ x,
                                                  const ushort_t* __restrict__ WT,
                                                  const float* __restrict__ benc,
                                                  const float* __restrict__ wout,
                                                  float* __restrict__ C_ws,
                                                  float* __restrict__ outbuf) {
    __shared__ __align__(16) ushort_t wlds[4 * 128 * 128];   // 128 KB, all layers
    const int tid = threadIdx.x;
    const int lane = tid & 63, wave = tid >> 6;
    const int m = lane & 31, Hh = lane >> 5;        // point-col, k-half

    // stage all 4 layers once: 8192 16B chunks, linear DMA
    #pragma unroll
    for (int c2 = 0; c2 < 16; ++c2) {
        int base = c2 * 512 + wave * 64;            // wave-uniform chunk base
        async_copy16(&wlds[base * 8], (const char*)WT + (base + lane) * 16);
    }
    __syncthreads();                                // drains DMA; ONLY barrier

    #pragma unroll 1
    for (int t = 0; t < 2; ++t) {
        const int pA = ((t * 256 + blockIdx.x) * 16 + wave * 2 + 0) * 32;
        const int pB = ((t * 256 + blockIdx.x) * 16 + wave * 2 + 1) * 32;

        uintx4 fA[8], fB[8], gA[8], gB[8];          // B-frags: k = ks*16 + Hh*8 + j

        // --- encoding straight into B-frags (dims 0-63 cos, 64-127 sin) ---
        {
            float2 xa = ((const float2*)x)[pA + m];
            float2 xb = ((const float2*)x)[pB + m];
            float a0 = 0.5f + 0.5f * xa.x, a1 = 0.5f + 0.5f * xa.y;
            float b0 = 0.5f + 0.5f * xb.x, b1 = 0.5f + 0.5f * xb.y;
            #pragma unroll
            for (int ks = 0; ks < 4; ++ks) {
                #pragma unroll
                for (int jp = 0; jp < 4; ++jp) {
                    int f = ks * 16 + Hh * 8 + jp * 2;
                    float4 bv = *(const float4*)&benc[2 * f];
                    float ta0 = __builtin_amdgcn_fractf(a0 * bv.x + a1 * bv.y);
                    float ta1 = __builtin_amdgcn_fractf(a0 * bv.z + a1 * bv.w);
                    float tb0 = __builtin_amdgcn_fractf(b0 * bv.x + b1 * bv.y);
                    float tb1 = __builtin_amdgcn_fractf(b0 * bv.z + b1 * bv.w);
                    fA[ks][jp]     = pk_bf16(__builtin_amdgcn_cosf(ta0), __builtin_amdgcn_cosf(ta1));
                    fA[ks + 4][jp] = pk_bf16(__builtin_amdgcn_sinf(ta0), __builtin_amdgcn_sinf(ta1));
                    fB[ks][jp]     = pk_bf16(__builtin_amdgcn_cosf(tb0), __builtin_amdgcn_cosf(tb1));
                    fB[ks + 4][jp] = pk_bf16(__builtin_amdgcn_sinf(tb0), __builtin_amdgcn_sinf(tb1));
                }
            }
        }

        run_layer(wlds,             m, Hh, fA, fB, gA, gB);   // layer 0
        run_layer(wlds + 16384,     m, Hh, gA, gB, fA, fB);   // layer 1
        run_layer(wlds + 2 * 16384, m, Hh, fA, fB, gA, gB);   // layer 2

        // layer 3 + final dot fused (per-i acc, no transform)
        float sA = 0.0f, sB = 0.0f;
        {
            const ushort_t* wl = wlds + 3 * 16384;
            #pragma unroll
            for (int i = 0; i < 4; ++i) {
                floatx16 aA = (floatx16)(0.0f), aB = (floatx16)(0.0f);
                #pragma unroll
                for (int ks = 0; ks < 8; ++ks) {
                    int n = i * 32 + m;
                    int cc = 2 * ks + Hh;
                    short8 av = *(const short8*)&wl[(n << 7) + ((cc ^ (n & 15)) << 3)];
                    aA = __builtin_amdgcn_mfma_f32_32x32x16_bf16(av, __builtin_bit_cast(short8, gA[ks]), aA, 0, 0, 0);
                    aB = __builtin_amdgcn_mfma_f32_32x32x16_bf16(av, __builtin_bit_cast(short8, gB[ks]), aB, 0, 0, 0);
                }
                #pragma unroll
                for (int rq = 0; rq < 4; ++rq) {
                    float4 wv = *(const float4*)&wout[i * 32 + rq * 8 + 4 * Hh];
                    sA += fmaxf(aA[rq * 4 + 0], 0.0f) * wv.x
                        + fmaxf(aA[rq * 4 + 1], 0.0f) * wv.y
                        + fmaxf(aA[rq * 4 + 2], 0.0f) * wv.z
                        + fmaxf(aA[rq * 4 + 3], 0.0f) * wv.w;
                    sB += fmaxf(aB[rq * 4 + 0], 0.0f) * wv.x
                        + fmaxf(aB[rq * 4 + 1], 0.0f) * wv.y
                        + fmaxf(aB[rq * 4 + 2], 0.0f) * wv.z
                        + fmaxf(aB[rq * 4 + 3], 0.0f) * wv.w;
                }
            }
        }
        sA += __shfl_xor(sA, 32);
        sB += __shfl_xor(sB, 32);
        if (Hh == 0) {
            C_ws[pA + m] = sA;
            outbuf[NPIX + pA + m] = sA;     // output 1: C
            C_ws[pB + m] = sB;
            outbuf[NPIX + pB + m] = sB;
        }
    }
}

// ---------------- fused: cost (box5 + Cs + V0) + 5 Jacobi passes ----------------
__global__ __launch_bounds__(256) void fused_solve_kernel(const int* __restrict__ bt,
                                                          const float* __restrict__ bc,
                                                          const float* __restrict__ C_ws,
                                                          float* __restrict__ Vfin) {
    __shared__ float Va[30 * 32];
    __shared__ float Vb[30 * 32];
    __shared__ float Wp[30 * 32];   // free -> Cs (>=0), pinned/out -> -(bc+1)
    const int tid = threadIdx.x;
    const int gx0 = (blockIdx.x & 31) * 16 - 7, gy0 = (blockIdx.x >> 5) * 16 - 7;

    for (int c = tid; c < 30 * 32; c += 256) {
        int li = c >> 5, lj = c & 31;
        int gi = gy0 + li, gj = gx0 + lj;
        float v = 0.0f;
        if (lj < 30 && gi >= 0 && gi < HH && gj >= 0 && gj < WW) {
            int g = gi * WW + gj;
            float b = bc[g];
            if (bt[g] == 1 && b > 0.0f) v = b;
        }
        Va[c] = v;
    }
    __syncthreads();

    for (int c = tid; c < 30 * 32; c += 256) {
        int li = c >> 5, lj = c & 31;
        int gi = gy0 + li, gj = gx0 + lj;
        float w = -1.0f, v0 = 0.0f;
        if (li >= 2 && li < 28 && lj >= 2 && lj < 28 &&
            gi >= 0 && gi < HH && gj >= 0 && gj < WW) {
            int g = gi * WW + gj;
            if (bt[g] == 0) {
                float s = 0.0f;
                #pragma unroll
                for (int di = 0; di < 5; ++di)
                    #pragma unroll
                    for (int dj = 0; dj < 5; ++dj)
                        s += Va[(li + di - 2) * 32 + lj + dj - 2];
                w = fmaxf(C_ws[g], 0.0f) + s * 0.04f;
                v0 = 100.0f;
            } else {
                float b = bc[g];
                w = -b - 1.0f;
                v0 = b;
            }
        }
        Wp[c] = w;
        Vb[c] = v0;
    }
    __syncthreads();

    float* src = Vb;
    float* dst = Va;
    #pragma unroll 1
    for (int t = 0; t < 5; ++t) {
        for (int c = tid; c < 26 * 32; c += 256) {
            int li = 2 + (c >> 5), lj = c & 31;
            if (lj < 2 || lj >= 28) continue;
            float w = Wp[li * 32 + lj];
            float v;
            if (w < 0.0f) {
                v = -w - 1.0f;
            } else {
                int gi = gy0 + li, gj = gx0 + lj;
                int um = (gi > 0)      ? li - 1 : li;
                int dp = (gi < HH - 1) ? li + 1 : li;
                int lm = (gj > 0)      ? lj - 1 : lj;
                int rp = (gj < WW - 1) ? lj + 1 : lj;
                float s = src[um * 32 + lm] + src[um * 32 + lj] + src[um * 32 + rp]
                        + src[li * 32 + lm]                     + src[li * 32 + rp]
                        + src[dp * 32 + lm] + src[dp * 32 + lj] + src[dp * 32 + rp];
                v = s * 0.125f + w;
            }
            dst[li * 32 + lj] = v;
        }
        __syncthreads();
        float* tmp = src; src = dst; dst = tmp;
    }

    {
        int li = 7 + (tid >> 4), lj = 7 + (tid & 15);
        Vfin[(gy0 + li) * WW + gx0 + lj] = src[li * 32 + lj];
    }
}

// ---------------- bilinear grid sample (align_corners, border clamp) ----------------
__global__ void sample_kernel(const float* __restrict__ x,
                              const float* __restrict__ V,
                              float* __restrict__ out) {
    int idx = blockIdx.x * 256 + threadIdx.x;
    float2 g2 = ((const float2*)x)[idx];
    float ix = (g2.x + 1.0f) * 0.5f * 511.0f;
    float iy = (g2.y + 1.0f) * 0.5f * 511.0f;
    ix = fminf(fmaxf(ix, 0.0f), 511.0f);
    iy = fminf(fmaxf(iy, 0.0f), 511.0f);
    int x0 = (int)floorf(ix), y0 = (int)floorf(iy);
    int x1 = min(x0 + 1, 511), y1 = min(y0 + 1, 511);
    float wx = ix - (float)x0, wy = iy - (float)y0;
    float v00 = V[y0 * 512 + x0], v01 = V[y0 * 512 + x1];
    float v10 = V[y1 * 512 + x0], v11 = V[y1 * 512 + x1];
    float v = v00 * (1.0f - wx) * (1.0f - wy) + v01 * wx * (1.0f - wy)
            + v10 * (1.0f - wx) * wy          + v11 * wx * wy;
    out[idx] = v;   // output 0
}

extern "C" void kernel_launch(void* const* d_in, const int* in_sizes, int n_in,
                              void* d_out, int out_size, void* d_ws, size_t ws_size,
                              hipStream_t stream) {
    const float* x    = (const float*)d_in[0];
    const int*   bt   = (const int*)d_in[1];
    const float* bc   = (const float*)d_in[2];
    const float* benc = (const float*)d_in[3];
    const float* Wh   = (const float*)d_in[4];
    const float* wout = (const float*)d_in[5];

    char* ws = (char*)d_ws;
    ushort_t* WT   = (ushort_t*)(ws + 4096);
    float*    C_ws = (float*)(ws + 262144);
    float*    Vfin = (float*)(ws + 262144 + 3 * (1 << 20));
    float*    outp = (float*)d_out;

    prep_kernel<<<16, 256, 0, stream>>>(Wh, WT);
    mlp_kernel<<<256, 512, 0, stream>>>(x, WT, benc, wout, C_ws, outp);
    fused_solve_kernel<<<1024, 256, 0, stream>>>(bt, bc, C_ws, Vfin);
    sample_kernel<<<1024, 256, 0, stream>>>(x, Vfin, outp);
}

// Round 14
// 125.520 us; speedup vs baseline: 2.5390x; 2.5390x over previous
//
#include <hip/hip_runtime.h>
#include <hip/hip_bf16.h>

// LaplaceCostNet — MI355X (gfx950), round 14.
// R11-R13 post-mortem: dual point-group needs ~190+ arch VGPRs; allocator caps
// MFMA kernels at 128 arch for 512-thr blocks regardless of bounds arg -> spills
// every time. Line abandoned. R14 = R10's proven single-group dataflow (124 regs,
// no spill) with 2-LAYER staging: LDS 128->64 KB, 2 blocks/CU, 3-4 waves/SIMD.
// Grid 1024 x 512thr, per block: enc -> L0,L1 -> barrier -> DMA L2,L3 -> barrier
// -> L2,L3 + fused dot. Extra barriers hidden by the co-resident block.
//
// Workspace (bytes):
//   [4096   .. 135168)   WT bf16: row n, physical 16B chunk P holds logical
//                        chunk P^(n&15)  (logical chunk cc = elems k=8cc..8cc+7)
//   [262144 .. +1MB)     C    fp32
//   [262144+3MB .. +4MB) Vfin fp32

typedef unsigned short ushort_t;
typedef short short8 __attribute__((ext_vector_type(8)));
typedef float floatx16 __attribute__((ext_vector_type(16)));
typedef unsigned int uintx4 __attribute__((ext_vector_type(4)));

#define HH 512
#define WW 512
#define NPIX (HH*WW)

__device__ inline unsigned int pk_bf16(float a, float b) {   // a->low16, b->high16
    __hip_bfloat162 h = __float22bfloat162_rn(float2{a, b});
    return *(unsigned int*)&h;
}
__device__ inline void async_copy16(void* lds, const void* g) {
    __builtin_amdgcn_global_load_lds(
        (const __attribute__((address_space(1))) unsigned int*)g,
        (__attribute__((address_space(3))) unsigned int*)lds, 16, 0, 0);
}

// ---------------- prep: DMA-ready swizzled WT (16B-chunk granularity) ----------------
__global__ __launch_bounds__(256) void prep_kernel(const float* __restrict__ Wh,
                                                   ushort_t* __restrict__ WT) {
    __shared__ float trans[32][129];
    const int t = threadIdx.x;
    const int l = blockIdx.x >> 2, n0 = (blockIdx.x & 3) * 32;
    const int nl = t & 31, k0 = t >> 5;            // k0 0..7
    #pragma unroll
    for (int pass = 0; pass < 16; ++pass) {
        int k = pass * 8 + k0;
        trans[nl][k] = Wh[l * 16384 + k * 128 + n0 + nl];   // coalesced in n
    }
    __syncthreads();
    #pragma unroll
    for (int c = 0; c < 2; ++c) {
        int idx = c * 256 + t;                      // 0..511 : 32 rows x 16 chunks
        int nl2 = idx >> 4, P = idx & 15;
        int n = n0 + nl2;
        int cc = P ^ (n & 15);                      // logical 16B chunk
        int kk = cc * 8;
        unsigned int w0 = pk_bf16(trans[nl2][kk + 0], trans[nl2][kk + 1]);
        unsigned int w1 = pk_bf16(trans[nl2][kk + 2], trans[nl2][kk + 3]);
        unsigned int w2 = pk_bf16(trans[nl2][kk + 4], trans[nl2][kk + 5]);
        unsigned int w3 = pk_bf16(trans[nl2][kk + 6], trans[nl2][kk + 7]);
        ((uint4*)WT)[(l * 128 + n) * 16 + P] = uint4{w0, w1, w2, w3};
    }
}

// ---------------- MLP: 2-layer staged, register-resident activations ----------------
__global__ __launch_bounds__(512, 2) void mlp_kernel(const float* __restrict__ x,
                                                     const ushort_t* __restrict__ WT,
                                                     const float* __restrict__ benc,
                                                     const float* __restrict__ wout,
                                                     float* __restrict__ C_ws,
                                                     float* __restrict__ outbuf) {
    __shared__ __align__(16) ushort_t wlds[2 * 128 * 128];   // 64 KB: two layers
    const int tid = threadIdx.x;
    const int lane = tid & 63, wave = tid >> 6;
    const int m = lane & 31, Hh = lane >> 5;        // point-col, k-half
    const int p0 = blockIdx.x * 256 + wave * 32;    // this wave's 32 points

    // stage layers 0,1 (64 KB = 4096 16B chunks, 8 per thread)
    #pragma unroll
    for (int c2 = 0; c2 < 8; ++c2) {
        int base = c2 * 512 + wave * 64;            // wave-uniform chunk base
        async_copy16(&wlds[base * 8], (const char*)WT + (base + lane) * 16);
    }

    uintx4 fragv[8];                                // B-frags: k = ks*16 + Hh*8 + j

    // --- encoding straight into B-frags (dims 0-63 cos, 64-127 sin) ---
    {
        float2 xv = ((const float2*)x)[p0 + m];
        float xq0 = 0.5f + 0.5f * xv.x, xq1 = 0.5f + 0.5f * xv.y;
        #pragma unroll
        for (int ks = 0; ks < 4; ++ks) {
            #pragma unroll
            for (int jp = 0; jp < 4; ++jp) {
                int f = ks * 16 + Hh * 8 + jp * 2;
                float4 b = *(const float4*)&benc[2 * f];
                float t0 = __builtin_amdgcn_fractf(xq0 * b.x + xq1 * b.y);
                float t1 = __builtin_amdgcn_fractf(xq0 * b.z + xq1 * b.w);
                fragv[ks][jp]     = pk_bf16(__builtin_amdgcn_cosf(t0),
                                            __builtin_amdgcn_cosf(t1));
                fragv[ks + 4][jp] = pk_bf16(__builtin_amdgcn_sinf(t0),
                                            __builtin_amdgcn_sinf(t1));
            }
        }
    }
    __syncthreads();                                // DMA(L0,L1) drained

    floatx16 acc[4];
    #pragma unroll 1
    for (int phase = 0; phase < 2; ++phase) {
        #pragma unroll 1
        for (int half = 0; half < 2; ++half) {      // layer l = 2*phase + half
            const ushort_t* wl = wlds + half * 16384;
            #pragma unroll
            for (int i = 0; i < 4; ++i) acc[i] = (floatx16)(0.0f);

            #pragma unroll
            for (int ks = 0; ks < 8; ++ks) {
                short8 bf = __builtin_bit_cast(short8, fragv[ks]);
                #pragma unroll
                for (int i = 0; i < 4; ++i) {
                    int n = i * 32 + m;
                    int cc = 2 * ks + Hh;                      // logical 16B chunk
                    short8 av = *(const short8*)&wl[(n << 7) + ((cc ^ (n & 15)) << 3)];
                    acc[i] = __builtin_amdgcn_mfma_f32_32x32x16_bf16(av, bf, acc[i], 0, 0, 0);
                }
            }

            if (phase == 1 && half == 1) break;     // layer 3: consumed below

            // C-layout -> next B-frags. Constant acc indices; Hh via selects.
            #pragma unroll
            for (int ks = 0; ks < 8; ++ks) {
                const int i = ks >> 1, par = ks & 1;
                unsigned int u0 = pk_bf16(fmaxf(acc[i][8 * par + 0], 0.0f),
                                          fmaxf(acc[i][8 * par + 1], 0.0f));
                unsigned int u1 = pk_bf16(fmaxf(acc[i][8 * par + 2], 0.0f),
                                          fmaxf(acc[i][8 * par + 3], 0.0f));
                unsigned int u2 = pk_bf16(fmaxf(acc[i][8 * par + 4], 0.0f),
                                          fmaxf(acc[i][8 * par + 5], 0.0f));
                unsigned int u3 = pk_bf16(fmaxf(acc[i][8 * par + 6], 0.0f),
                                          fmaxf(acc[i][8 * par + 7], 0.0f));
                unsigned int s0 = Hh ? u0 : u2, s1 = Hh ? u1 : u3;
                unsigned int k0 = Hh ? u2 : u0, k1 = Hh ? u3 : u1;
                unsigned int r0 = (unsigned int)__shfl_xor((int)s0, 32);
                unsigned int r1 = (unsigned int)__shfl_xor((int)s1, 32);
                fragv[ks][0] = Hh ? r0 : k0;
                fragv[ks][1] = Hh ? r1 : k1;
                fragv[ks][2] = Hh ? k0 : r0;
                fragv[ks][3] = Hh ? k1 : r1;
            }
        }

        if (phase == 0) {
            __syncthreads();                        // all reads of L0,L1 done
            // stage layers 2,3 into the same buffer
            #pragma unroll
            for (int c2 = 0; c2 < 8; ++c2) {
                int base = c2 * 512 + wave * 64;
                async_copy16(&wlds[base * 8],
                             (const char*)WT + 65536 + (base + lane) * 16);
            }
            __syncthreads();                        // DMA(L2,L3) drained
        }
    }

    // final dot from layer-3 accumulators: n = i*32 + (r&3) + 8*(r>>2) + 4*Hh
    float s = 0.0f;
    #pragma unroll
    for (int i = 0; i < 4; ++i) {
        #pragma unroll
        for (int rq = 0; rq < 4; ++rq) {
            float4 wv = *(const float4*)&wout[i * 32 + rq * 8 + 4 * Hh];
            s += fmaxf(acc[i][rq * 4 + 0], 0.0f) * wv.x
               + fmaxf(acc[i][rq * 4 + 1], 0.0f) * wv.y
               + fmaxf(acc[i][rq * 4 + 2], 0.0f) * wv.z
               + fmaxf(acc[i][rq * 4 + 3], 0.0f) * wv.w;
        }
    }
    s += __shfl_xor(s, 32);
    if (Hh == 0) {
        C_ws[p0 + m] = s;
        outbuf[NPIX + p0 + m] = s;                  // output 1: C
    }
}

// ---------------- fused: cost (box5 + Cs + V0) + 5 Jacobi passes ----------------
__global__ __launch_bounds__(256) void fused_solve_kernel(const int* __restrict__ bt,
                                                          const float* __restrict__ bc,
                                                          const float* __restrict__ C_ws,
                                                          float* __restrict__ Vfin) {
    __shared__ float Va[30 * 32];
    __shared__ float Vb[30 * 32];
    __shared__ float Wp[30 * 32];   // free -> Cs (>=0), pinned/out -> -(bc+1)
    const int tid = threadIdx.x;
    const int gx0 = (blockIdx.x & 31) * 16 - 7, gy0 = (blockIdx.x >> 5) * 16 - 7;

    for (int c = tid; c < 30 * 32; c += 256) {
        int li = c >> 5, lj = c & 31;
        int gi = gy0 + li, gj = gx0 + lj;
        float v = 0.0f;
        if (lj < 30 && gi >= 0 && gi < HH && gj >= 0 && gj < WW) {
            int g = gi * WW + gj;
            float b = bc[g];
            if (bt[g] == 1 && b > 0.0f) v = b;
        }
        Va[c] = v;
    }
    __syncthreads();

    for (int c = tid; c < 30 * 32; c += 256) {
        int li = c >> 5, lj = c & 31;
        int gi = gy0 + li, gj = gx0 + lj;
        float w = -1.0f, v0 = 0.0f;
        if (li >= 2 && li < 28 && lj >= 2 && lj < 28 &&
            gi >= 0 && gi < HH && gj >= 0 && gj < WW) {
            int g = gi * WW + gj;
            if (bt[g] == 0) {
                float s = 0.0f;
                #pragma unroll
                for (int di = 0; di < 5; ++di)
                    #pragma unroll
                    for (int dj = 0; dj < 5; ++dj)
                        s += Va[(li + di - 2) * 32 + lj + dj - 2];
                w = fmaxf(C_ws[g], 0.0f) + s * 0.04f;
                v0 = 100.0f;
            } else {
                float b = bc[g];
                w = -b - 1.0f;
                v0 = b;
            }
        }
        Wp[c] = w;
        Vb[c] = v0;
    }
    __syncthreads();

    float* src = Vb;
    float* dst = Va;
    #pragma unroll 1
    for (int t = 0; t < 5; ++t) {
        for (int c = tid; c < 26 * 32; c += 256) {
            int li = 2 + (c >> 5), lj = c & 31;
            if (lj < 2 || lj >= 28) continue;
            float w = Wp[li * 32 + lj];
            float v;
            if (w < 0.0f) {
                v = -w - 1.0f;
            } else {
                int gi = gy0 + li, gj = gx0 + lj;
                int um = (gi > 0)      ? li - 1 : li;
                int dp = (gi < HH - 1) ? li + 1 : li;
                int lm = (gj > 0)      ? lj - 1 : lj;
                int rp = (gj < WW - 1) ? lj + 1 : lj;
                float s = src[um * 32 + lm] + src[um * 32 + lj] + src[um * 32 + rp]
                        + src[li * 32 + lm]                     + src[li * 32 + rp]
                        + src[dp * 32 + lm] + src[dp * 32 + lj] + src[dp * 32 + rp];
                v = s * 0.125f + w;
            }
            dst[li * 32 + lj] = v;
        }
        __syncthreads();
        float* tmp = src; src = dst; dst = tmp;
    }

    {
        int li = 7 + (tid >> 4), lj = 7 + (tid & 15);
        Vfin[(gy0 + li) * WW + gx0 + lj] = src[li * 32 + lj];
    }
}

// ---------------- bilinear grid sample (align_corners, border clamp) ----------------
__global__ void sample_kernel(const float* __restrict__ x,
                              const float* __restrict__ V,
                              float* __restrict__ out) {
    int idx = blockIdx.x * 256 + threadIdx.x;
    float2 g2 = ((const float2*)x)[idx];
    float ix = (g2.x + 1.0f) * 0.5f * 511.0f;
    float iy = (g2.y + 1.0f) * 0.5f * 511.0f;
    ix = fminf(fmaxf(ix, 0.0f), 511.0f);
    iy = fminf(fmaxf(iy, 0.0f), 511.0f);
    int x0 = (int)floorf(ix), y0 = (int)floorf(iy);
    int x1 = min(x0 + 1, 511), y1 = min(y0 + 1, 511);
    float wx = ix - (float)x0, wy = iy - (float)y0;
    float v00 = V[y0 * 512 + x0], v01 = V[y0 * 512 + x1];
    float v10 = V[y1 * 512 + x0], v11 = V[y1 * 512 + x1];
    float v = v00 * (1.0f - wx) * (1.0f - wy) + v01 * wx * (1.0f - wy)
            + v10 * (1.0f - wx) * wy          + v11 * wx * wy;
    out[idx] = v;   // output 0
}

extern "C" void kernel_launch(void* const* d_in, const int* in_sizes, int n_in,
                              void* d_out, int out_size, void* d_ws, size_t ws_size,
                              hipStream_t stream) {
    const float* x    = (const float*)d_in[0];
    const int*   bt   = (const int*)d_in[1];
    const float* bc   = (const float*)d_in[2];
    const float* benc = (const float*)d_in[3];
    const float* Wh   = (const float*)d_in[4];
    const float* wout = (const float*)d_in[5];

    char* ws = (char*)d_ws;
    ushort_t* WT   = (ushort_t*)(ws + 4096);
    float*    C_ws = (float*)(ws + 262144);
    float*    Vfin = (float*)(ws + 262144 + 3 * (1 << 20));
    float*    outp = (float*)d_out;

    prep_kernel<<<16, 256, 0, stream>>>(Wh, WT);
    mlp_kernel<<<1024, 512, 0, stream>>>(x, WT, benc, wout, C_ws, outp);
    fused_solve_kernel<<<1024, 256, 0, stream>>>(bt, bc, C_ws, Vfin);
    sample_kernel<<<1024, 256, 0, stream>>>(x, Vfin, outp);
}

// Round 15
// 121.956 us; speedup vs baseline: 2.6132x; 1.0292x over previous
//
#include <hip/hip_runtime.h>
#include <hip/hip_bf16.h>

// LaplaceCostNet — MI355X (gfx950), round 15.
// R14 ledger: total = mlp + ~7 µs small kernels + ~68 µs FIXED harness overhead
// (constant across 4..9 dispatches). Only mlp matters. R14 mlp = 50 µs at
// 2 blocks/CU (64 KB LDS), VGPR 76 (6 waves/SIMD capable). R15: single-layer
// 32 KB staging -> 3 blocks/CU (wave-limited by 76 regs), per-layer double
// barrier with register xform overlapping the DMA. LDS traffic unchanged
// (floor ~20.5 µs/CU); block co-residency 1.5x to hide chain stalls.
//
// Workspace (bytes):
//   [4096   .. 135168)   WT bf16: row n, physical 16B chunk P holds logical
//                        chunk P^(n&15)  (logical chunk cc = elems k=8cc..8cc+7)
//   [262144 .. +1MB)     C    fp32
//   [262144+3MB .. +4MB) Vfin fp32

typedef unsigned short ushort_t;
typedef short short8 __attribute__((ext_vector_type(8)));
typedef float floatx16 __attribute__((ext_vector_type(16)));
typedef unsigned int uintx4 __attribute__((ext_vector_type(4)));

#define HH 512
#define WW 512
#define NPIX (HH*WW)

__device__ inline unsigned int pk_bf16(float a, float b) {   // a->low16, b->high16
    __hip_bfloat162 h = __float22bfloat162_rn(float2{a, b});
    return *(unsigned int*)&h;
}
__device__ inline void async_copy16(void* lds, const void* g) {
    __builtin_amdgcn_global_load_lds(
        (const __attribute__((address_space(1))) unsigned int*)g,
        (__attribute__((address_space(3))) unsigned int*)lds, 16, 0, 0);
}

// ---------------- prep: DMA-ready swizzled WT (16B-chunk granularity) ----------------
__global__ __launch_bounds__(256) void prep_kernel(const float* __restrict__ Wh,
                                                   ushort_t* __restrict__ WT) {
    __shared__ float trans[32][129];
    const int t = threadIdx.x;
    const int l = blockIdx.x >> 2, n0 = (blockIdx.x & 3) * 32;
    const int nl = t & 31, k0 = t >> 5;            // k0 0..7
    #pragma unroll
    for (int pass = 0; pass < 16; ++pass) {
        int k = pass * 8 + k0;
        trans[nl][k] = Wh[l * 16384 + k * 128 + n0 + nl];   // coalesced in n
    }
    __syncthreads();
    #pragma unroll
    for (int c = 0; c < 2; ++c) {
        int idx = c * 256 + t;                      // 0..511 : 32 rows x 16 chunks
        int nl2 = idx >> 4, P = idx & 15;
        int n = n0 + nl2;
        int cc = P ^ (n & 15);                      // logical 16B chunk
        int kk = cc * 8;
        unsigned int w0 = pk_bf16(trans[nl2][kk + 0], trans[nl2][kk + 1]);
        unsigned int w1 = pk_bf16(trans[nl2][kk + 2], trans[nl2][kk + 3]);
        unsigned int w2 = pk_bf16(trans[nl2][kk + 4], trans[nl2][kk + 5]);
        unsigned int w3 = pk_bf16(trans[nl2][kk + 6], trans[nl2][kk + 7]);
        ((uint4*)WT)[(l * 128 + n) * 16 + P] = uint4{w0, w1, w2, w3};
    }
}

// ---------------- MLP: 1-layer staged (32 KB), register-resident activations ----------------
__global__ __launch_bounds__(512, 2) void mlp_kernel(const float* __restrict__ x,
                                                     const ushort_t* __restrict__ WT,
                                                     const float* __restrict__ benc,
                                                     const float* __restrict__ wout,
                                                     float* __restrict__ C_ws,
                                                     float* __restrict__ outbuf) {
    __shared__ __align__(16) ushort_t wlds[128 * 128];   // 32 KB: ONE layer
    const int tid = threadIdx.x;
    const int lane = tid & 63, wave = tid >> 6;
    const int m = lane & 31, Hh = lane >> 5;        // point-col, k-half
    const int p0 = blockIdx.x * 256 + wave * 32;    // this wave's 32 points

    // stage layer 0 (32 KB = 2048 16B chunks, 4 per thread)
    #pragma unroll
    for (int c2 = 0; c2 < 4; ++c2) {
        int base = c2 * 512 + wave * 64;            // wave-uniform chunk base
        async_copy16(&wlds[base * 8], (const char*)WT + (base + lane) * 16);
    }

    uintx4 fragv[8];                                // B-frags: k = ks*16 + Hh*8 + j

    // --- encoding straight into B-frags (dims 0-63 cos, 64-127 sin) ---
    {
        float2 xv = ((const float2*)x)[p0 + m];
        float xq0 = 0.5f + 0.5f * xv.x, xq1 = 0.5f + 0.5f * xv.y;
        #pragma unroll
        for (int ks = 0; ks < 4; ++ks) {
            #pragma unroll
            for (int jp = 0; jp < 4; ++jp) {
                int f = ks * 16 + Hh * 8 + jp * 2;
                float4 b = *(const float4*)&benc[2 * f];
                float t0 = __builtin_amdgcn_fractf(xq0 * b.x + xq1 * b.y);
                float t1 = __builtin_amdgcn_fractf(xq0 * b.z + xq1 * b.w);
                fragv[ks][jp]     = pk_bf16(__builtin_amdgcn_cosf(t0),
                                            __builtin_amdgcn_cosf(t1));
                fragv[ks + 4][jp] = pk_bf16(__builtin_amdgcn_sinf(t0),
                                            __builtin_amdgcn_sinf(t1));
            }
        }
    }
    __syncthreads();                                // DMA(L0) drained

    floatx16 acc[4];
    #pragma unroll 1
    for (int l = 0; l < 4; ++l) {
        #pragma unroll
        for (int i = 0; i < 4; ++i) acc[i] = (floatx16)(0.0f);

        #pragma unroll
        for (int ks = 0; ks < 8; ++ks) {
            short8 bf = __builtin_bit_cast(short8, fragv[ks]);
            #pragma unroll
            for (int i = 0; i < 4; ++i) {
                int n = i * 32 + m;
                int cc = 2 * ks + Hh;                      // logical 16B chunk
                short8 av = *(const short8*)&wlds[(n << 7) + ((cc ^ (n & 15)) << 3)];
                acc[i] = __builtin_amdgcn_mfma_f32_32x32x16_bf16(av, bf, acc[i], 0, 0, 0);
            }
        }
        if (l == 3) break;                          // layer-3 acc consumed below

        __syncthreads();                            // all reads of layer l done

        // issue DMA of layer l+1, then do the register-only transform while it flies
        #pragma unroll
        for (int c2 = 0; c2 < 4; ++c2) {
            int base = c2 * 512 + wave * 64;
            async_copy16(&wlds[base * 8],
                         (const char*)WT + (l + 1) * 32768 + (base + lane) * 16);
        }

        // C-layout -> next B-frags. Constant acc indices; Hh via selects.
        #pragma unroll
        for (int ks = 0; ks < 8; ++ks) {
            const int i = ks >> 1, par = ks & 1;
            unsigned int u0 = pk_bf16(fmaxf(acc[i][8 * par + 0], 0.0f),
                                      fmaxf(acc[i][8 * par + 1], 0.0f));
            unsigned int u1 = pk_bf16(fmaxf(acc[i][8 * par + 2], 0.0f),
                                      fmaxf(acc[i][8 * par + 3], 0.0f));
            unsigned int u2 = pk_bf16(fmaxf(acc[i][8 * par + 4], 0.0f),
                                      fmaxf(acc[i][8 * par + 5], 0.0f));
            unsigned int u3 = pk_bf16(fmaxf(acc[i][8 * par + 6], 0.0f),
                                      fmaxf(acc[i][8 * par + 7], 0.0f));
            unsigned int s0 = Hh ? u0 : u2, s1 = Hh ? u1 : u3;
            unsigned int k0 = Hh ? u2 : u0, k1 = Hh ? u3 : u1;
            unsigned int r0 = (unsigned int)__shfl_xor((int)s0, 32);
            unsigned int r1 = (unsigned int)__shfl_xor((int)s1, 32);
            fragv[ks][0] = Hh ? r0 : k0;
            fragv[ks][1] = Hh ? r1 : k1;
            fragv[ks][2] = Hh ? k0 : r0;
            fragv[ks][3] = Hh ? k1 : r1;
        }

        __syncthreads();                            // DMA(l+1) drained
    }

    // final dot from layer-3 accumulators: n = i*32 + (r&3) + 8*(r>>2) + 4*Hh
    float s = 0.0f;
    #pragma unroll
    for (int i = 0; i < 4; ++i) {
        #pragma unroll
        for (int rq = 0; rq < 4; ++rq) {
            float4 wv = *(const float4*)&wout[i * 32 + rq * 8 + 4 * Hh];
            s += fmaxf(acc[i][rq * 4 + 0], 0.0f) * wv.x
               + fmaxf(acc[i][rq * 4 + 1], 0.0f) * wv.y
               + fmaxf(acc[i][rq * 4 + 2], 0.0f) * wv.z
               + fmaxf(acc[i][rq * 4 + 3], 0.0f) * wv.w;
        }
    }
    s += __shfl_xor(s, 32);
    if (Hh == 0) {
        C_ws[p0 + m] = s;
        outbuf[NPIX + p0 + m] = s;                  // output 1: C
    }
}

// ---------------- fused: cost (box5 + Cs + V0) + 5 Jacobi passes ----------------
__global__ __launch_bounds__(256) void fused_solve_kernel(const int* __restrict__ bt,
                                                          const float* __restrict__ bc,
                                                          const float* __restrict__ C_ws,
                                                          float* __restrict__ Vfin) {
    __shared__ float Va[30 * 32];
    __shared__ float Vb[30 * 32];
    __shared__ float Wp[30 * 32];   // free -> Cs (>=0), pinned/out -> -(bc+1)
    const int tid = threadIdx.x;
    const int gx0 = (blockIdx.x & 31) * 16 - 7, gy0 = (blockIdx.x >> 5) * 16 - 7;

    for (int c = tid; c < 30 * 32; c += 256) {
        int li = c >> 5, lj = c & 31;
        int gi = gy0 + li, gj = gx0 + lj;
        float v = 0.0f;
        if (lj < 30 && gi >= 0 && gi < HH && gj >= 0 && gj < WW) {
            int g = gi * WW + gj;
            float b = bc[g];
            if (bt[g] == 1 && b > 0.0f) v = b;
        }
        Va[c] = v;
    }
    __syncthreads();

    for (int c = tid; c < 30 * 32; c += 256) {
        int li = c >> 5, lj = c & 31;
        int gi = gy0 + li, gj = gx0 + lj;
        float w = -1.0f, v0 = 0.0f;
        if (li >= 2 && li < 28 && lj >= 2 && lj < 28 &&
            gi >= 0 && gi < HH && gj >= 0 && gj < WW) {
            int g = gi * WW + gj;
            if (bt[g] == 0) {
                float s = 0.0f;
                #pragma unroll
                for (int di = 0; di < 5; ++di)
                    #pragma unroll
                    for (int dj = 0; dj < 5; ++dj)
                        s += Va[(li + di - 2) * 32 + lj + dj - 2];
                w = fmaxf(C_ws[g], 0.0f) + s * 0.04f;
                v0 = 100.0f;
            } else {
                float b = bc[g];
                w = -b - 1.0f;
                v0 = b;
            }
        }
        Wp[c] = w;
        Vb[c] = v0;
    }
    __syncthreads();

    float* src = Vb;
    float* dst = Va;
    #pragma unroll 1
    for (int t = 0; t < 5; ++t) {
        for (int c = tid; c < 26 * 32; c += 256) {
            int li = 2 + (c >> 5), lj = c & 31;
            if (lj < 2 || lj >= 28) continue;
            float w = Wp[li * 32 + lj];
            float v;
            if (w < 0.0f) {
                v = -w - 1.0f;
            } else {
                int gi = gy0 + li, gj = gx0 + lj;
                int um = (gi > 0)      ? li - 1 : li;
                int dp = (gi < HH - 1) ? li + 1 : li;
                int lm = (gj > 0)      ? lj - 1 : lj;
                int rp = (gj < WW - 1) ? lj + 1 : lj;
                float s = src[um * 32 + lm] + src[um * 32 + lj] + src[um * 32 + rp]
                        + src[li * 32 + lm]                     + src[li * 32 + rp]
                        + src[dp * 32 + lm] + src[dp * 32 + lj] + src[dp * 32 + rp];
                v = s * 0.125f + w;
            }
            dst[li * 32 + lj] = v;
        }
        __syncthreads();
        float* tmp = src; src = dst; dst = tmp;
    }

    {
        int li = 7 + (tid >> 4), lj = 7 + (tid & 15);
        Vfin[(gy0 + li) * WW + gx0 + lj] = src[li * 32 + lj];
    }
}

// ---------------- bilinear grid sample (align_corners, border clamp) ----------------
__global__ void sample_kernel(const float* __restrict__ x,
                              const float* __restrict__ V,
                              float* __restrict__ out) {
    int idx = blockIdx.x * 256 + threadIdx.x;
    float2 g2 = ((const float2*)x)[idx];
    float ix = (g2.x + 1.0f) * 0.5f * 511.0f;
    float iy = (g2.y + 1.0f) * 0.5f * 511.0f;
    ix = fminf(fmaxf(ix, 0.0f), 511.0f);
    iy = fminf(fmaxf(iy, 0.0f), 511.0f);
    int x0 = (int)floorf(ix), y0 = (int)floorf(iy);
    int x1 = min(x0 + 1, 511), y1 = min(y0 + 1, 511);
    float wx = ix - (float)x0, wy = iy - (float)y0;
    float v00 = V[y0 * 512 + x0], v01 = V[y0 * 512 + x1];
    float v10 = V[y1 * 512 + x0], v11 = V[y1 * 512 + x1];
    float v = v00 * (1.0f - wx) * (1.0f - wy) + v01 * wx * (1.0f - wy)
            + v10 * (1.0f - wx) * wy          + v11 * wx * wy;
    out[idx] = v;   // output 0
}

extern "C" void kernel_launch(void* const* d_in, const int* in_sizes, int n_in,
                              void* d_out, int out_size, void* d_ws, size_t ws_size,
                              hipStream_t stream) {
    const float* x    = (const float*)d_in[0];
    const int*   bt   = (const int*)d_in[1];
    const float* bc   = (const float*)d_in[2];
    const float* benc = (const float*)d_in[3];
    const float* Wh   = (const float*)d_in[4];
    const float* wout = (const float*)d_in[5];

    char* ws = (char*)d_ws;
    ushort_t* WT   = (ushort_t*)(ws + 4096);
    float*    C_ws = (float*)(ws + 262144);
    float*    Vfin = (float*)(ws + 262144 + 3 * (1 << 20));
    float*    outp = (float*)d_out;

    prep_kernel<<<16, 256, 0, stream>>>(Wh, WT);
    mlp_kernel<<<1024, 512, 0, stream>>>(x, WT, benc, wout, C_ws, outp);
    fused_solve_kernel<<<1024, 256, 0, stream>>>(bt, bc, C_ws, Vfin);
    sample_kernel<<<1024, 256, 0, stream>>>(x, Vfin, outp);
}

// Round 16
// 120.212 us; speedup vs baseline: 2.6511x; 1.0145x over previous
//
#include <hip/hip_runtime.h>
#include <hip/hip_bf16.h>

// LaplaceCostNet — MI355X (gfx950), round 16.
// R15 invariant: time tracks LDS-pipe totals (A-frag b128 stream + xform's 48
// ds_bpermute shuffles/thread). R16: K-PERMUTED WEIGHTS — prep stores layer l+1
// weights with k-order pi(slot)=i*32+par*16+4Hh+(j&3)+8*(j>>2), which equals the
// MFMA C/D ownership of lane (m,Hh). Inter-layer transform becomes pure
// in-lane relu+pack (NO shfl, NO cndmask). Encoding fills slots via the same
// map (ks<4 cos, ks>=4 sin). Bit-identical numerics.
//
// Workspace (bytes):
//   [4096   .. 135168)   WT bf16: row n, physical 16B chunk P = cc^(n&15),
//                        chunk cc=2ks+Hh holds slots j=0..7 -> Wh[l][pi][n]
//   [262144 .. +1MB)     C    fp32
//   [262144+3MB .. +4MB) Vfin fp32

typedef unsigned short ushort_t;
typedef short short8 __attribute__((ext_vector_type(8)));
typedef float floatx16 __attribute__((ext_vector_type(16)));
typedef unsigned int uintx4 __attribute__((ext_vector_type(4)));

#define HH 512
#define WW 512
#define NPIX (HH*WW)

__device__ inline unsigned int pk_bf16(float a, float b) {   // a->low16, b->high16
    __hip_bfloat162 h = __float22bfloat162_rn(float2{a, b});
    return *(unsigned int*)&h;
}
__device__ inline void async_copy16(void* lds, const void* g) {
    __builtin_amdgcn_global_load_lds(
        (const __attribute__((address_space(1))) unsigned int*)g,
        (__attribute__((address_space(3))) unsigned int*)lds, 16, 0, 0);
}

// ---------------- prep: DMA-ready swizzled + K-PERMUTED WT ----------------
__global__ __launch_bounds__(256) void prep_kernel(const float* __restrict__ Wh,
                                                   ushort_t* __restrict__ WT) {
    __shared__ float trans[32][129];
    const int t = threadIdx.x;
    const int l = blockIdx.x >> 2, n0 = (blockIdx.x & 3) * 32;
    const int nl = t & 31, k0 = t >> 5;            // k0 0..7
    #pragma unroll
    for (int pass = 0; pass < 16; ++pass) {
        int k = pass * 8 + k0;
        trans[nl][k] = Wh[l * 16384 + k * 128 + n0 + nl];   // coalesced in n
    }
    __syncthreads();
    #pragma unroll
    for (int c = 0; c < 2; ++c) {
        int idx = c * 256 + t;                      // 0..511 : 32 rows x 16 chunks
        int nl2 = idx >> 4, P = idx & 15;
        int n = n0 + nl2;
        int cc = P ^ (n & 15);                      // logical chunk = 2*ks + Hh
        int ks = cc >> 1, Hq = cc & 1;
        int base = (ks >> 1) * 32 + (ks & 1) * 16 + Hq * 4;   // pi base
        // slots j=0..7 -> k_src = base + (j&3) + 8*(j>>2)
        unsigned int w0 = pk_bf16(trans[nl2][base + 0],  trans[nl2][base + 1]);
        unsigned int w1 = pk_bf16(trans[nl2][base + 2],  trans[nl2][base + 3]);
        unsigned int w2 = pk_bf16(trans[nl2][base + 8],  trans[nl2][base + 9]);
        unsigned int w3 = pk_bf16(trans[nl2][base + 10], trans[nl2][base + 11]);
        ((uint4*)WT)[(l * 128 + n) * 16 + P] = uint4{w0, w1, w2, w3};
    }
}

// ---------------- MLP: 1-layer staged (32 KB), register-resident, shuffle-free ----------------
__global__ __launch_bounds__(512, 2) void mlp_kernel(const float* __restrict__ x,
                                                     const ushort_t* __restrict__ WT,
                                                     const float* __restrict__ benc,
                                                     const float* __restrict__ wout,
                                                     float* __restrict__ C_ws,
                                                     float* __restrict__ outbuf) {
    __shared__ __align__(16) ushort_t wlds[128 * 128];   // 32 KB: ONE layer
    const int tid = threadIdx.x;
    const int lane = tid & 63, wave = tid >> 6;
    const int m = lane & 31, Hh = lane >> 5;        // point-col, k-half
    const int p0 = blockIdx.x * 256 + wave * 32;    // this wave's 32 points

    // stage layer 0 (32 KB = 2048 16B chunks, 4 per thread)
    #pragma unroll
    for (int c2 = 0; c2 < 4; ++c2) {
        int base = c2 * 512 + wave * 64;            // wave-uniform chunk base
        async_copy16(&wlds[base * 8], (const char*)WT + (base + lane) * 16);
    }

    uintx4 fragv[8];                                // B-frags in pi-slot order

    // --- encoding into pi-ordered slots: slot(ks,Hh,j) holds enc[pi] where
    //     pi = i*32+par*16+4Hh+(j&3)+8*(j>>2); i>=2 (ks>=4) -> sin, else cos ---
    {
        float2 xv = ((const float2*)x)[p0 + m];
        float xq0 = 0.5f + 0.5f * xv.x, xq1 = 0.5f + 0.5f * xv.y;
        #pragma unroll
        for (int ks = 0; ks < 8; ++ks) {
            const int i = ks >> 1, par = ks & 1;
            #pragma unroll
            for (int jp = 0; jp < 4; ++jp) {
                int nu = i * 32 + par * 16 + Hh * 4 + (jp & 1) * 2 + (jp >> 1) * 8;
                int f = nu & 63;                    // freq index (nu>=64 -> sin)
                float4 b = *(const float4*)&benc[2 * f];
                float t0 = __builtin_amdgcn_fractf(xq0 * b.x + xq1 * b.y);
                float t1 = __builtin_amdgcn_fractf(xq0 * b.z + xq1 * b.w);
                float v0, v1;
                if (ks < 4) { v0 = __builtin_amdgcn_cosf(t0); v1 = __builtin_amdgcn_cosf(t1); }
                else        { v0 = __builtin_amdgcn_sinf(t0); v1 = __builtin_amdgcn_sinf(t1); }
                fragv[ks][jp] = pk_bf16(v0, v1);
            }
        }
    }
    __syncthreads();                                // DMA(L0) drained

    floatx16 acc[4];
    #pragma unroll 1
    for (int l = 0; l < 4; ++l) {
        #pragma unroll
        for (int i = 0; i < 4; ++i) acc[i] = (floatx16)(0.0f);

        #pragma unroll
        for (int ks = 0; ks < 8; ++ks) {
            short8 bf = __builtin_bit_cast(short8, fragv[ks]);
            #pragma unroll
            for (int i = 0; i < 4; ++i) {
                int n = i * 32 + m;
                int cc = 2 * ks + Hh;                      // logical 16B chunk
                short8 av = *(const short8*)&wlds[(n << 7) + ((cc ^ (n & 15)) << 3)];
                acc[i] = __builtin_amdgcn_mfma_f32_32x32x16_bf16(av, bf, acc[i], 0, 0, 0);
            }
        }
        if (l == 3) break;                          // layer-3 acc consumed below

        __syncthreads();                            // all reads of layer l done

        // issue DMA of layer l+1; register-only transform overlaps the copy
        #pragma unroll
        for (int c2 = 0; c2 < 4; ++c2) {
            int base = c2 * 512 + wave * 64;
            async_copy16(&wlds[base * 8],
                         (const char*)WT + (l + 1) * 32768 + (base + lane) * 16);
        }

        // C -> next B-frags: PURE in-lane relu+pack (pi-matched, no shuffles)
        #pragma unroll
        for (int ks = 0; ks < 8; ++ks) {
            const int i = ks >> 1, par = ks & 1;
            fragv[ks][0] = pk_bf16(fmaxf(acc[i][8 * par + 0], 0.0f),
                                   fmaxf(acc[i][8 * par + 1], 0.0f));
            fragv[ks][1] = pk_bf16(fmaxf(acc[i][8 * par + 2], 0.0f),
                                   fmaxf(acc[i][8 * par + 3], 0.0f));
            fragv[ks][2] = pk_bf16(fmaxf(acc[i][8 * par + 4], 0.0f),
                                   fmaxf(acc[i][8 * par + 5], 0.0f));
            fragv[ks][3] = pk_bf16(fmaxf(acc[i][8 * par + 6], 0.0f),
                                   fmaxf(acc[i][8 * par + 7], 0.0f));
        }

        __syncthreads();                            // DMA(l+1) drained
    }

    // final dot from layer-3 accumulators: n = i*32 + (r&3) + 8*(r>>2) + 4*Hh
    float s = 0.0f;
    #pragma unroll
    for (int i = 0; i < 4; ++i) {
        #pragma unroll
        for (int rq = 0; rq < 4; ++rq) {
            float4 wv = *(const float4*)&wout[i * 32 + rq * 8 + 4 * Hh];
            s += fmaxf(acc[i][rq * 4 + 0], 0.0f) * wv.x
               + fmaxf(acc[i][rq * 4 + 1], 0.0f) * wv.y
               + fmaxf(acc[i][rq * 4 + 2], 0.0f) * wv.z
               + fmaxf(acc[i][rq * 4 + 3], 0.0f) * wv.w;
        }
    }
    s += __shfl_xor(s, 32);
    if (Hh == 0) {
        C_ws[p0 + m] = s;
        outbuf[NPIX + p0 + m] = s;                  // output 1: C
    }
}

// ---------------- fused: cost (box5 + Cs + V0) + 5 Jacobi passes ----------------
__global__ __launch_bounds__(256) void fused_solve_kernel(const int* __restrict__ bt,
                                                          const float* __restrict__ bc,
                                                          const float* __restrict__ C_ws,
                                                          float* __restrict__ Vfin) {
    __shared__ float Va[30 * 32];
    __shared__ float Vb[30 * 32];
    __shared__ float Wp[30 * 32];   // free -> Cs (>=0), pinned/out -> -(bc+1)
    const int tid = threadIdx.x;
    const int gx0 = (blockIdx.x & 31) * 16 - 7, gy0 = (blockIdx.x >> 5) * 16 - 7;

    for (int c = tid; c < 30 * 32; c += 256) {
        int li = c >> 5, lj = c & 31;
        int gi = gy0 + li, gj = gx0 + lj;
        float v = 0.0f;
        if (lj < 30 && gi >= 0 && gi < HH && gj >= 0 && gj < WW) {
            int g = gi * WW + gj;
            float b = bc[g];
            if (bt[g] == 1 && b > 0.0f) v = b;
        }
        Va[c] = v;
    }
    __syncthreads();

    for (int c = tid; c < 30 * 32; c += 256) {
        int li = c >> 5, lj = c & 31;
        int gi = gy0 + li, gj = gx0 + lj;
        float w = -1.0f, v0 = 0.0f;
        if (li >= 2 && li < 28 && lj >= 2 && lj < 28 &&
            gi >= 0 && gi < HH && gj >= 0 && gj < WW) {
            int g = gi * WW + gj;
            if (bt[g] == 0) {
                float s = 0.0f;
                #pragma unroll
                for (int di = 0; di < 5; ++di)
                    #pragma unroll
                    for (int dj = 0; dj < 5; ++dj)
                        s += Va[(li + di - 2) * 32 + lj + dj - 2];
                w = fmaxf(C_ws[g], 0.0f) + s * 0.04f;
                v0 = 100.0f;
            } else {
                float b = bc[g];
                w = -b - 1.0f;
                v0 = b;
            }
        }
        Wp[c] = w;
        Vb[c] = v0;
    }
    __syncthreads();

    float* src = Vb;
    float* dst = Va;
    #pragma unroll 1
    for (int t = 0; t < 5; ++t) {
        for (int c = tid; c < 26 * 32; c += 256) {
            int li = 2 + (c >> 5), lj = c & 31;
            if (lj < 2 || lj >= 28) continue;
            float w = Wp[li * 32 + lj];
            float v;
            if (w < 0.0f) {
                v = -w - 1.0f;
            } else {
                int gi = gy0 + li, gj = gx0 + lj;
                int um = (gi > 0)      ? li - 1 : li;
                int dp = (gi < HH - 1) ? li + 1 : li;
                int lm = (gj > 0)      ? lj - 1 : lj;
                int rp = (gj < WW - 1) ? lj + 1 : lj;
                float s = src[um * 32 + lm] + src[um * 32 + lj] + src[um * 32 + rp]
                        + src[li * 32 + lm]                     + src[li * 32 + rp]
                        + src[dp * 32 + lm] + src[dp * 32 + lj] + src[dp * 32 + rp];
                v = s * 0.125f + w;
            }
            dst[li * 32 + lj] = v;
        }
        __syncthreads();
        float* tmp = src; src = dst; dst = tmp;
    }

    {
        int li = 7 + (tid >> 4), lj = 7 + (tid & 15);
        Vfin[(gy0 + li) * WW + gx0 + lj] = src[li * 32 + lj];
    }
}

// ---------------- bilinear grid sample (align_corners, border clamp) ----------------
__global__ void sample_kernel(const float* __restrict__ x,
                              const float* __restrict__ V,
                              float* __restrict__ out) {
    int idx = blockIdx.x * 256 + threadIdx.x;
    float2 g2 = ((const float2*)x)[idx];
    float ix = (g2.x + 1.0f) * 0.5f * 511.0f;
    float iy = (g2.y + 1.0f) * 0.5f * 511.0f;
    ix = fminf(fmaxf(ix, 0.0f), 511.0f);
    iy = fminf(fmaxf(iy, 0.0f), 511.0f);
    int x0 = (int)floorf(ix), y0 = (int)floorf(iy);
    int x1 = min(x0 + 1, 511), y1 = min(y0 + 1, 511);
    float wx = ix - (float)x0, wy = iy - (float)y0;
    float v00 = V[y0 * 512 + x0], v01 = V[y0 * 512 + x1];
    float v10 = V[y1 * 512 + x0], v11 = V[y1 * 512 + x1];
    float v = v00 * (1.0f - wx) * (1.0f - wy) + v01 * wx * (1.0f - wy)
            + v10 * (1.0f - wx) * wy          + v11 * wx * wy;
    out[idx] = v;   // output 0
}

extern "C" void kernel_launch(void* const* d_in, const int* in_sizes, int n_in,
                              void* d_out, int out_size, void* d_ws, size_t ws_size,
                              hipStream_t stream) {
    const float* x    = (const float*)d_in[0];
    const int*   bt   = (const int*)d_in[1];
    const float* bc   = (const float*)d_in[2];
    const float* benc = (const float*)d_in[3];
    const float* Wh   = (const float*)d_in[4];
    const float* wout = (const float*)d_in[5];

    char* ws = (char*)d_ws;
    ushort_t* WT   = (ushort_t*)(ws + 4096);
    float*    C_ws = (float*)(ws + 262144);
    float*    Vfin = (float*)(ws + 262144 + 3 * (1 << 20));
    float*    outp = (float*)d_out;

    prep_kernel<<<16, 256, 0, stream>>>(Wh, WT);
    mlp_kernel<<<1024, 512, 0, stream>>>(x, WT, benc, wout, C_ws, outp);
    fused_solve_kernel<<<1024, 256, 0, stream>>>(bt, bc, C_ws, Vfin);
    sample_kernel<<<1024, 256, 0, stream>>>(x, Vfin, outp);
}

// Round 17
// 118.128 us; speedup vs baseline: 2.6979x; 1.0176x over previous
//
#include <hip/hip_runtime.h>
#include <hip/hip_bf16.h>

// LaplaceCostNet — MI355X (gfx950), round 17.
// R16 falsified DS-saturation (removing 48 bpermutes: no change). Pipes sum
// instead of overlap -> phase-serialized; biggest VALU block = per-read address
// math. R17: (a) inner(ks)+i*8192+buf*32768 decomposition (n&15==m&15 is
// i-independent) -> ds_read offset immediates, inner[8] computed ONCE;
// (b) 2-buffer LDS (64 KB), barriers 7->4. Numerics bit-identical to R16.
//
// Workspace (bytes):
//   [4096   .. 135168)   WT bf16: row n, physical 16B chunk P = cc^(n&15),
//                        chunk cc=2ks+Hh holds pi-permuted k slots (R16 map)
//   [262144 .. +1MB)     C    fp32
//   [262144+3MB .. +4MB) Vfin fp32

typedef unsigned short ushort_t;
typedef short short8 __attribute__((ext_vector_type(8)));
typedef float floatx16 __attribute__((ext_vector_type(16)));
typedef unsigned int uintx4 __attribute__((ext_vector_type(4)));

#define HH 512
#define WW 512
#define NPIX (HH*WW)

__device__ inline unsigned int pk_bf16(float a, float b) {   // a->low16, b->high16
    __hip_bfloat162 h = __float22bfloat162_rn(float2{a, b});
    return *(unsigned int*)&h;
}
__device__ inline void async_copy16(void* lds, const void* g) {
    __builtin_amdgcn_global_load_lds(
        (const __attribute__((address_space(1))) unsigned int*)g,
        (__attribute__((address_space(3))) unsigned int*)lds, 16, 0, 0);
}

// ---------------- prep: DMA-ready swizzled + K-PERMUTED WT (R16) ----------------
__global__ __launch_bounds__(256) void prep_kernel(const float* __restrict__ Wh,
                                                   ushort_t* __restrict__ WT) {
    __shared__ float trans[32][129];
    const int t = threadIdx.x;
    const int l = blockIdx.x >> 2, n0 = (blockIdx.x & 3) * 32;
    const int nl = t & 31, k0 = t >> 5;            // k0 0..7
    #pragma unroll
    for (int pass = 0; pass < 16; ++pass) {
        int k = pass * 8 + k0;
        trans[nl][k] = Wh[l * 16384 + k * 128 + n0 + nl];   // coalesced in n
    }
    __syncthreads();
    #pragma unroll
    for (int c = 0; c < 2; ++c) {
        int idx = c * 256 + t;                      // 0..511 : 32 rows x 16 chunks
        int nl2 = idx >> 4, P = idx & 15;
        int n = n0 + nl2;
        int cc = P ^ (n & 15);                      // logical chunk = 2*ks + Hh
        int ks = cc >> 1, Hq = cc & 1;
        int base = (ks >> 1) * 32 + (ks & 1) * 16 + Hq * 4;   // pi base
        unsigned int w0 = pk_bf16(trans[nl2][base + 0],  trans[nl2][base + 1]);
        unsigned int w1 = pk_bf16(trans[nl2][base + 2],  trans[nl2][base + 3]);
        unsigned int w2 = pk_bf16(trans[nl2][base + 8],  trans[nl2][base + 9]);
        unsigned int w3 = pk_bf16(trans[nl2][base + 10], trans[nl2][base + 11]);
        ((uint4*)WT)[(l * 128 + n) * 16 + P] = uint4{w0, w1, w2, w3};
    }
}

// one layer K-loop from LDS buffer BUF; addresses = inner[ks] + i*8192 (immediates)
template<int BUF>
__device__ __forceinline__ void klayer(const ushort_t* __restrict__ wlds,
                                       const int (&inn)[8],
                                       const uintx4 (&fragv)[8],
                                       floatx16 (&acc)[4]) {
    #pragma unroll
    for (int i = 0; i < 4; ++i) acc[i] = (floatx16)(0.0f);
    #pragma unroll
    for (int ks = 0; ks < 8; ++ks) {
        short8 bf = __builtin_bit_cast(short8, fragv[ks]);
        #pragma unroll
        for (int i = 0; i < 4; ++i) {
            short8 av = *(const short8*)((const char*)wlds + BUF * 32768 + i * 8192 + inn[ks]);
            acc[i] = __builtin_amdgcn_mfma_f32_32x32x16_bf16(av, bf, acc[i], 0, 0, 0);
        }
    }
}

// C -> next B-frags: pure in-lane relu+pack (pi-matched, no shuffles)
__device__ __forceinline__ void xform_all(uintx4 (&fragv)[8], const floatx16 (&acc)[4]) {
    #pragma unroll
    for (int ks = 0; ks < 8; ++ks) {
        const int i = ks >> 1, par = ks & 1;
        fragv[ks][0] = pk_bf16(fmaxf(acc[i][8 * par + 0], 0.0f),
                               fmaxf(acc[i][8 * par + 1], 0.0f));
        fragv[ks][1] = pk_bf16(fmaxf(acc[i][8 * par + 2], 0.0f),
                               fmaxf(acc[i][8 * par + 3], 0.0f));
        fragv[ks][2] = pk_bf16(fmaxf(acc[i][8 * par + 4], 0.0f),
                               fmaxf(acc[i][8 * par + 5], 0.0f));
        fragv[ks][3] = pk_bf16(fmaxf(acc[i][8 * par + 6], 0.0f),
                               fmaxf(acc[i][8 * par + 7], 0.0f));
    }
}

__device__ __forceinline__ void stage_layer(ushort_t* wlds, int buf,
                                            const char* src, int wave, int lane) {
    #pragma unroll
    for (int c2 = 0; c2 < 4; ++c2) {
        int base = c2 * 512 + wave * 64;            // wave-uniform chunk base
        async_copy16(&wlds[buf * 16384 + base * 8], src + (base + lane) * 16);
    }
}

// ---------------- MLP: double-buffered, shuffle-free, immediate-offset reads ----------------
__global__ __launch_bounds__(512, 2) void mlp_kernel(const float* __restrict__ x,
                                                     const ushort_t* __restrict__ WT,
                                                     const float* __restrict__ benc,
                                                     const float* __restrict__ wout,
                                                     float* __restrict__ C_ws,
                                                     float* __restrict__ outbuf) {
    __shared__ __align__(16) ushort_t wlds[2 * 128 * 128];   // 64 KB: two buffers
    const int tid = threadIdx.x;
    const int lane = tid & 63, wave = tid >> 6;
    const int m = lane & 31, Hh = lane >> 5;        // point-col, k-half
    const int p0 = blockIdx.x * 256 + wave * 32;    // this wave's 32 points

    stage_layer(wlds, 0, (const char*)WT, wave, lane);            // L0 -> b0
    stage_layer(wlds, 1, (const char*)WT + 32768, wave, lane);    // L1 -> b1

    // per-lane byte offsets, i-independent (n&15 == m&15): computed ONCE
    int inn[8];
    #pragma unroll
    for (int ks = 0; ks < 8; ++ks)
        inn[ks] = m * 256 + ((((2 * ks + Hh) ^ (m & 15))) << 4);

    uintx4 fragv[8];                                // B-frags in pi-slot order

    // --- encoding into pi-ordered slots (R16 map: ks<4 cos, ks>=4 sin) ---
    {
        float2 xv = ((const float2*)x)[p0 + m];
        float xq0 = 0.5f + 0.5f * xv.x, xq1 = 0.5f + 0.5f * xv.y;
        #pragma unroll
        for (int ks = 0; ks < 8; ++ks) {
            const int i = ks >> 1, par = ks & 1;
            #pragma unroll
            for (int jp = 0; jp < 4; ++jp) {
                int nu = i * 32 + par * 16 + Hh * 4 + (jp & 1) * 2 + (jp >> 1) * 8;
                int f = nu & 63;                    // freq index (nu>=64 -> sin)
                float4 b = *(const float4*)&benc[2 * f];
                float t0 = __builtin_amdgcn_fractf(xq0 * b.x + xq1 * b.y);
                float t1 = __builtin_amdgcn_fractf(xq0 * b.z + xq1 * b.w);
                float v0, v1;
                if (ks < 4) { v0 = __builtin_amdgcn_cosf(t0); v1 = __builtin_amdgcn_cosf(t1); }
                else        { v0 = __builtin_amdgcn_sinf(t0); v1 = __builtin_amdgcn_sinf(t1); }
                fragv[ks][jp] = pk_bf16(v0, v1);
            }
        }
    }
    __syncthreads();                                // drains L0+L1 DMA

    floatx16 acc[4];
    klayer<0>(wlds, inn, fragv, acc);               // layer 0 from b0
    __syncthreads();                                // b0 reads done
    stage_layer(wlds, 0, (const char*)WT + 2 * 32768, wave, lane);  // L2 -> b0
    xform_all(fragv, acc);
    klayer<1>(wlds, inn, fragv, acc);               // layer 1 from b1
    __syncthreads();                                // drains L2 DMA; b1 reads done
    stage_layer(wlds, 1, (const char*)WT + 3 * 32768, wave, lane);  // L3 -> b1
    xform_all(fragv, acc);
    klayer<0>(wlds, inn, fragv, acc);               // layer 2 from b0
    __syncthreads();                                // drains L3 DMA
    xform_all(fragv, acc);
    klayer<1>(wlds, inn, fragv, acc);               // layer 3 from b1

    // final dot from layer-3 accumulators: n = i*32 + (r&3) + 8*(r>>2) + 4*Hh
    float s = 0.0f;
    #pragma unroll
    for (int i = 0; i < 4; ++i) {
        #pragma unroll
        for (int rq = 0; rq < 4; ++rq) {
            float4 wv = *(const float4*)&wout[i * 32 + rq * 8 + 4 * Hh];
            s += fmaxf(acc[i][rq * 4 + 0], 0.0f) * wv.x
               + fmaxf(acc[i][rq * 4 + 1], 0.0f) * wv.y
               + fmaxf(acc[i][rq * 4 + 2], 0.0f) * wv.z
               + fmaxf(acc[i][rq * 4 + 3], 0.0f) * wv.w;
        }
    }
    s += __shfl_xor(s, 32);
    if (Hh == 0) {
        C_ws[p0 + m] = s;
        outbuf[NPIX + p0 + m] = s;                  // output 1: C
    }
}

// ---------------- fused: cost (box5 + Cs + V0) + 5 Jacobi passes ----------------
__global__ __launch_bounds__(256) void fused_solve_kernel(const int* __restrict__ bt,
                                                          const float* __restrict__ bc,
                                                          const float* __restrict__ C_ws,
                                                          float* __restrict__ Vfin) {
    __shared__ float Va[30 * 32];
    __shared__ float Vb[30 * 32];
    __shared__ float Wp[30 * 32];   // free -> Cs (>=0), pinned/out -> -(bc+1)
    const int tid = threadIdx.x;
    const int gx0 = (blockIdx.x & 31) * 16 - 7, gy0 = (blockIdx.x >> 5) * 16 - 7;

    for (int c = tid; c < 30 * 32; c += 256) {
        int li = c >> 5, lj = c & 31;
        int gi = gy0 + li, gj = gx0 + lj;
        float v = 0.0f;
        if (lj < 30 && gi >= 0 && gi < HH && gj >= 0 && gj < WW) {
            int g = gi * WW + gj;
            float b = bc[g];
            if (bt[g] == 1 && b > 0.0f) v = b;
        }
        Va[c] = v;
    }
    __syncthreads();

    for (int c = tid; c < 30 * 32; c += 256) {
        int li = c >> 5, lj = c & 31;
        int gi = gy0 + li, gj = gx0 + lj;
        float w = -1.0f, v0 = 0.0f;
        if (li >= 2 && li < 28 && lj >= 2 && lj < 28 &&
            gi >= 0 && gi < HH && gj >= 0 && gj < WW) {
            int g = gi * WW + gj;
            if (bt[g] == 0) {
                float s = 0.0f;
                #pragma unroll
                for (int di = 0; di < 5; ++di)
                    #pragma unroll
                    for (int dj = 0; dj < 5; ++dj)
                        s += Va[(li + di - 2) * 32 + lj + dj - 2];
                w = fmaxf(C_ws[g], 0.0f) + s * 0.04f;
                v0 = 100.0f;
            } else {
                float b = bc[g];
                w = -b - 1.0f;
                v0 = b;
            }
        }
        Wp[c] = w;
        Vb[c] = v0;
    }
    __syncthreads();

    float* src = Vb;
    float* dst = Va;
    #pragma unroll 1
    for (int t = 0; t < 5; ++t) {
        for (int c = tid; c < 26 * 32; c += 256) {
            int li = 2 + (c >> 5), lj = c & 31;
            if (lj < 2 || lj >= 28) continue;
            float w = Wp[li * 32 + lj];
            float v;
            if (w < 0.0f) {
                v = -w - 1.0f;
            } else {
                int gi = gy0 + li, gj = gx0 + lj;
                int um = (gi > 0)      ? li - 1 : li;
                int dp = (gi < HH - 1) ? li + 1 : li;
                int lm = (gj > 0)      ? lj - 1 : lj;
                int rp = (gj < WW - 1) ? lj + 1 : lj;
                float s = src[um * 32 + lm] + src[um * 32 + lj] + src[um * 32 + rp]
                        + src[li * 32 + lm]                     + src[li * 32 + rp]
                        + src[dp * 32 + lm] + src[dp * 32 + lj] + src[dp * 32 + rp];
                v = s * 0.125f + w;
            }
            dst[li * 32 + lj] = v;
        }
        __syncthreads();
        float* tmp = src; src = dst; dst = tmp;
    }

    {
        int li = 7 + (tid >> 4), lj = 7 + (tid & 15);
        Vfin[(gy0 + li) * WW + gx0 + lj] = src[li * 32 + lj];
    }
}

// ---------------- bilinear grid sample (align_corners, border clamp) ----------------
__global__ void sample_kernel(const float* __restrict__ x,
                              const float* __restrict__ V,
                              float* __restrict__ out) {
    int idx = blockIdx.x * 256 + threadIdx.x;
    float2 g2 = ((const float2*)x)[idx];
    float ix = (g2.x + 1.0f) * 0.5f * 511.0f;
    float iy = (g2.y + 1.0f) * 0.5f * 511.0f;
    ix = fminf(fmaxf(ix, 0.0f), 511.0f);
    iy = fminf(fmaxf(iy, 0.0f), 511.0f);
    int x0 = (int)floorf(ix), y0 = (int)floorf(iy);
    int x1 = min(x0 + 1, 511), y1 = min(y0 + 1, 511);
    float wx = ix - (float)x0, wy = iy - (float)y0;
    float v00 = V[y0 * 512 + x0], v01 = V[y0 * 512 + x1];
    float v10 = V[y1 * 512 + x0], v11 = V[y1 * 512 + x1];
    float v = v00 * (1.0f - wx) * (1.0f - wy) + v01 * wx * (1.0f - wy)
            + v10 * (1.0f - wx) * wy          + v11 * wx * wy;
    out[idx] = v;   // output 0
}

extern "C" void kernel_launch(void* const* d_in, const int* in_sizes, int n_in,
                              void* d_out, int out_size, void* d_ws, size_t ws_size,
                              hipStream_t stream) {
    const float* x    = (const float*)d_in[0];
    const int*   bt   = (const int*)d_in[1];
    const float* bc   = (const float*)d_in[2];
    const float* benc = (const float*)d_in[3];
    const float* Wh   = (const float*)d_in[4];
    const float* wout = (const float*)d_in[5];

    char* ws = (char*)d_ws;
    ushort_t* WT   = (ushort_t*)(ws + 4096);
    float*    C_ws = (float*)(ws + 262144);
    float*    Vfin = (float*)(ws + 262144 + 3 * (1 << 20));
    float*    outp = (float*)d_out;

    prep_kernel<<<16, 256, 0, stream>>>(Wh, WT);
    mlp_kernel<<<1024, 512, 0, stream>>>(x, WT, benc, wout, C_ws, outp);
    fused_solve_kernel<<<1024, 256, 0, stream>>>(bt, bc, C_ws, Vfin);
    sample_kernel<<<1024, 256, 0, stream>>>(x, Vfin, outp);
}